// Round 5
// baseline (84.640 us; speedup 1.0000x reference)
//
#include <hip/hip_runtime.h>

// SE3Transform: out_pos[m*N+n] = R[batch[n]+16m] @ xyz[n] + p[batch[n]+16m]
//               out_batch[m*N+n] = batch[n] + 16m (as float)
// N=500000, B=16, M=8. Floor: 64MB W + ~10MB R => ~11.4us @6.3TB/s.
//
// R3 lesson: structural rewrite (serial LDS round-trip -> independent
// pipelined stores) moved dur_us by 0.06us => either kernel is a minor
// component of the timed iteration, or an external limiter is shared.
// R4/R5 isolates the one shared candidate: L2 write-allocate thrash from
// the 64MB output stream sweeping the 32MB L2. Change vs R3: ALL output
// stores are non-temporal (nt bypasses L2 allocation). R5 fixes the R4
// compile error: __builtin_nontemporal_store needs a native clang vector
// type, not HIP_vector_type.

#define NPTS   500000
#define POSF4  375000     // pos float4s per m-slice
#define BATF4  125000     // batch float4s per m-slice
#define NT     128
#define TSTR   20         // dword stride per matrix in LDS (bank spread)

typedef float vf4 __attribute__((ext_vector_type(4)));   // nt-store-compatible

__global__ __launch_bounds__(256) void se3_kernel(
    const float* __restrict__ trans,   // [128,4,4]
    const float* __restrict__ xyz,     // [N,3]
    const int*   __restrict__ batch,   // [N]
    float* __restrict__ out)           // [12M pos floats][4M batch floats]
{
    __shared__ float  s_t[NT * TSTR];  // 10,240 B
    __shared__ float4 s_x[264];        //  4,224 B: xyz f4 window [F-2, F+262)

    const int tid = threadIdx.x;
    const int F   = blockIdx.x * 256;
    const int t   = F + tid;

    // Stage trans -> LDS (512 f4, 2/thread). Row c of matrix nb at dword
    // nb*20 + c*4 = [Rc0 Rc1 Rc2 pc].
    for (int i = tid; i < NT * 4; i += 256) {
        int pt = i >> 2, row = i & 3;
        float4 v = ((const float4*)trans)[i];
        *(float4*)&s_t[pt * TSTR + row * 4] = v;
    }
    // Stage xyz window for pos blocks (coalesced f4 loads, clamped).
    if (F < POSF4) {
        for (int i = tid; i < 264; i += 256) {
            int idx = F - 2 + i;
            idx = idx < 0 ? 0 : (idx >= POSF4 ? POSF4 - 1 : idx);
            s_x[i] = ((const float4*)xyz)[idx];
        }
    }
    __syncthreads();

    if (t < POSF4) {
        const int f  = t;
        const int t3 = f % 3;
        const int n0 = (4 * f - t3) / 3;         // first point this f4 touches

        // 6 xyz floats [4f-t3 .. 4f-t3+5] from the window.
        const float* sxf = (const float*)s_x;
        const int off = 4 * tid + 8 - t3;
        float xa = sxf[off + 0], xb = sxf[off + 1], xc = sxf[off + 2];
        float xd = sxf[off + 3], xe = sxf[off + 4], xf = sxf[off + 5];

        const int b0 = batch[n0];
        const int b1 = batch[n0 + 1];

        // Per output comp k: c_k=(t3+k)%3, sel_k=(t3+k)/3; m-invariant
        // byte offset into s_t, and the point's xyz comps.
        int   ro[4];
        float X0[4], X1[4], X2[4];
        #pragma unroll
        for (int k = 0; k < 4; ++k) {
            int ck = t3 + k, sel = 0;
            if (ck >= 3) { ck -= 3; sel = 1; }
            int b = sel ? b1 : b0;
            ro[k] = b * (TSTR * 4) + ck * 16;    // bytes
            X0[k] = sel ? xd : xa;
            X1[k] = sel ? xe : xb;
            X2[k] = sel ? xf : xc;
        }

        const char* stb = (const char*)s_t;
        vf4* po = (vf4*)out;
        #pragma unroll
        for (int m = 0; m < 8; ++m) {
            // m stride = 16 matrices * 20 dwords * 4B = 1280B (imm offset)
            float4 r0 = *(const float4*)(stb + ro[0] + m * 1280);
            float4 r1 = *(const float4*)(stb + ro[1] + m * 1280);
            float4 r2 = *(const float4*)(stb + ro[2] + m * 1280);
            float4 r3 = *(const float4*)(stb + ro[3] + m * 1280);
            vf4 v;
            v.x = fmaf(r0.x, X0[0], fmaf(r0.y, X1[0], fmaf(r0.z, X2[0], r0.w)));
            v.y = fmaf(r1.x, X0[1], fmaf(r1.y, X1[1], fmaf(r1.z, X2[1], r1.w)));
            v.z = fmaf(r2.x, X0[2], fmaf(r2.y, X1[2], fmaf(r2.z, X2[2], r2.w)));
            v.w = fmaf(r3.x, X0[3], fmaf(r3.y, X1[3], fmaf(r3.z, X2[3], r3.w)));
            __builtin_nontemporal_store(v, &po[m * POSF4 + f]);  // coalesced, L2-bypass
        }
    } else if (t < POSF4 + BATF4) {
        const int q = t - POSF4;
        int4 b4 = ((const int4*)batch)[q];
        vf4* ob = (vf4*)(out + 12000000);
        #pragma unroll
        for (int m = 0; m < 8; ++m) {
            const int a = m * 16;
            vf4 v;
            v.x = (float)(b4.x + a);
            v.y = (float)(b4.y + a);
            v.z = (float)(b4.z + a);
            v.w = (float)(b4.w + a);
            __builtin_nontemporal_store(v, &ob[m * BATF4 + q]);
        }
    }
}

extern "C" void kernel_launch(void* const* d_in, const int* in_sizes, int n_in,
                              void* d_out, int out_size, void* d_ws, size_t ws_size,
                              hipStream_t stream) {
    const float* trans = (const float*)d_in[0];   // 2048 floats
    const float* xyz   = (const float*)d_in[1];   // 1,500,000 floats
    const int*   batch = (const int*)d_in[2];     // 500,000 ints
    float* out = (float*)d_out;                   // 16,000,000 floats

    const int total = POSF4 + BATF4;              // 500,000 work items
    const int block = 256;
    const int grid  = (total + block - 1) / block; // 1954
    se3_kernel<<<grid, block, 0, stream>>>(trans, xyz, batch, out);
}

// Round 6
// 83.233 us; speedup vs baseline: 1.0169x; 1.0169x over previous
//
#include <hip/hip_runtime.h>

// SE3Transform: out_pos[m*N+n] = R[batch[n]+16m] @ xyz[n] + p[batch[n]+16m]
//               out_batch[m*N+n] = batch[n] + 16m (as float)
// N=500000, B=16, M=8. Kernel floor: 64MB W + ~10MB R => ~11.4us @6.3TB/s.
//
// FINAL (R3 structure, re-adopted after R5):
//  - R1: 48B-stride f4 stores, 87.7us total. Union-contiguous per wave, so
//    L2 write-combining kept HBM traffic merged; only ~5us extra L2 txns.
//  - R2: wave-local LDS output transpose, 82.8us.
//  - R3: thread<->output-f4 direct coalesced stores, all 8 m-iterations
//    independent/pipelined, 82.7us  <-- best.
//  - R5: R3 + nontemporal stores, 84.6us => L2 write-thrash NOT the
//    limiter; reverted.
// Conclusion: kernel is store-BW-bound at ~its 11-15us floor inside a
// ~70us fixed harness envelope (256MiB d_ws poison ~45us + 64MB d_out
// poison ~11us + restores + graph gaps). Three structural rewrites moved
// totals only within fill-variance noise (+-2us) => roofline.
//
// Per-thread: output float4 f of the 1.5M-float pos stream needs rows
// c_k=(t3+k)%3 of matrices A=(4f-t3)/3, B=A+1 (t3=f%3). Row offsets into
// s_trans are m-invariant; per m: 4 ds_read_b128 + 12 fma + 1 coalesced
// store_dwordx4. Tail threads (t>=375000) stream the batch output.

#define NPTS   500000
#define POSF4  375000     // pos float4s per m-slice
#define BATF4  125000     // batch float4s per m-slice
#define NT     128
#define TSTR   20         // dword stride per matrix in LDS (bank spread)

__global__ __launch_bounds__(256) void se3_kernel(
    const float* __restrict__ trans,   // [128,4,4]
    const float* __restrict__ xyz,     // [N,3]
    const int*   __restrict__ batch,   // [N]
    float* __restrict__ out)           // [12M pos floats][4M batch floats]
{
    __shared__ float  s_t[NT * TSTR];  // 10,240 B
    __shared__ float4 s_x[264];        //  4,224 B: xyz f4 window [F-2, F+262)

    const int tid = threadIdx.x;
    const int F   = blockIdx.x * 256;
    const int t   = F + tid;

    // Stage trans -> LDS (512 f4, 2/thread). Row c of matrix nb at dword
    // nb*20 + c*4 = [Rc0 Rc1 Rc2 pc].
    for (int i = tid; i < NT * 4; i += 256) {
        int pt = i >> 2, row = i & 3;
        float4 v = ((const float4*)trans)[i];
        *(float4*)&s_t[pt * TSTR + row * 4] = v;
    }
    // Stage xyz window for pos blocks (coalesced f4 loads, clamped).
    if (F < POSF4) {
        for (int i = tid; i < 264; i += 256) {
            int idx = F - 2 + i;
            idx = idx < 0 ? 0 : (idx >= POSF4 ? POSF4 - 1 : idx);
            s_x[i] = ((const float4*)xyz)[idx];
        }
    }
    __syncthreads();

    if (t < POSF4) {
        const int f  = t;
        const int t3 = f % 3;
        const int n0 = (4 * f - t3) / 3;         // first point this f4 touches

        // 6 xyz floats [4f-t3 .. 4f-t3+5] from the window.
        const float* sxf = (const float*)s_x;
        const int off = 4 * tid + 8 - t3;
        float xa = sxf[off + 0], xb = sxf[off + 1], xc = sxf[off + 2];
        float xd = sxf[off + 3], xe = sxf[off + 4], xf = sxf[off + 5];

        const int b0 = batch[n0];
        const int b1 = batch[n0 + 1];

        // Per output comp k: c_k=(t3+k)%3, sel_k=(t3+k)/3; m-invariant
        // byte offset into s_t, and the point's xyz comps.
        int   ro[4];
        float X0[4], X1[4], X2[4];
        #pragma unroll
        for (int k = 0; k < 4; ++k) {
            int ck = t3 + k, sel = 0;
            if (ck >= 3) { ck -= 3; sel = 1; }
            int b = sel ? b1 : b0;
            ro[k] = b * (TSTR * 4) + ck * 16;    // bytes
            X0[k] = sel ? xd : xa;
            X1[k] = sel ? xe : xb;
            X2[k] = sel ? xf : xc;
        }

        const char* stb = (const char*)s_t;
        float4* po = (float4*)out;
        #pragma unroll
        for (int m = 0; m < 8; ++m) {
            // m stride = 16 matrices * 20 dwords * 4B = 1280B (imm offset)
            float4 r0 = *(const float4*)(stb + ro[0] + m * 1280);
            float4 r1 = *(const float4*)(stb + ro[1] + m * 1280);
            float4 r2 = *(const float4*)(stb + ro[2] + m * 1280);
            float4 r3 = *(const float4*)(stb + ro[3] + m * 1280);
            float4 v;
            v.x = fmaf(r0.x, X0[0], fmaf(r0.y, X1[0], fmaf(r0.z, X2[0], r0.w)));
            v.y = fmaf(r1.x, X0[1], fmaf(r1.y, X1[1], fmaf(r1.z, X2[1], r1.w)));
            v.z = fmaf(r2.x, X0[2], fmaf(r2.y, X1[2], fmaf(r2.z, X2[2], r2.w)));
            v.w = fmaf(r3.x, X0[3], fmaf(r3.y, X1[3], fmaf(r3.z, X2[3], r3.w)));
            po[m * POSF4 + f] = v;               // lane-contiguous, coalesced
        }
    } else if (t < POSF4 + BATF4) {
        const int q = t - POSF4;
        int4 b4 = ((const int4*)batch)[q];
        float4* ob = (float4*)(out + 12000000);
        #pragma unroll
        for (int m = 0; m < 8; ++m) {
            const int a = m * 16;
            ob[m * BATF4 + q] = make_float4((float)(b4.x + a), (float)(b4.y + a),
                                            (float)(b4.z + a), (float)(b4.w + a));
        }
    }
}

extern "C" void kernel_launch(void* const* d_in, const int* in_sizes, int n_in,
                              void* d_out, int out_size, void* d_ws, size_t ws_size,
                              hipStream_t stream) {
    const float* trans = (const float*)d_in[0];   // 2048 floats
    const float* xyz   = (const float*)d_in[1];   // 1,500,000 floats
    const int*   batch = (const int*)d_in[2];     // 500,000 ints
    float* out = (float*)d_out;                   // 16,000,000 floats

    const int total = POSF4 + BATF4;              // 500,000 work items
    const int block = 256;
    const int grid  = (total + block - 1) / block; // 1954
    se3_kernel<<<grid, block, 0, stream>>>(trans, xyz, batch, out);
}